// Round 1
// baseline (528.711 us; speedup 1.0000x reference)
//
#include <hip/hip_runtime.h>
#include <math.h>

// ---------- types / helpers ----------
typedef __attribute__((ext_vector_type(8))) short short8;   // 8 bf16 (4 VGPRs)
typedef __attribute__((ext_vector_type(4))) float f32x4;    // MFMA acc

#define MFMA16(a, b, c) __builtin_amdgcn_mfma_f32_16x16x32_bf16((a), (b), (c), 0, 0, 0)

// async global->LDS, 16B per lane. LDS dest is wave-uniform base + lane*16.
__device__ inline void gl_lds16(const void* g, void* l) {
  __builtin_amdgcn_global_load_lds(
      (const __attribute__((address_space(1))) void*)g,
      (__attribute__((address_space(3))) void*)l, 16, 0, 0);
}

// pack two f32 -> two bf16 (truncation; bias ~2^-9, fine vs 0.2475 threshold)
__device__ inline unsigned int pack2(float lo, float hi) {
  unsigned int ulo = __float_as_uint(lo), uhi = __float_as_uint(hi);
  return (uhi & 0xFFFF0000u) | (ulo >> 16);
}
// round-to-nearest (ties up) f32 -> bf16
__device__ inline unsigned short f2bf_r(float f) {
  return (unsigned short)((__float_as_uint(f) + 0x8000u) >> 16);
}
__device__ inline float bf2f(unsigned short h) {
  return __uint_as_float(((unsigned int)h) << 16);
}

// ---------- K0: repack W1 [3,2048,128] f32 -> W1bt [384,2048] bf16 (B^T, k-contiguous) ----------
__global__ __launch_bounds__(256) void k_repack_w1(const float* __restrict__ W1,
                                                   unsigned short* __restrict__ W1bt) {
  __shared__ float tile[64 * 128];   // 32 KB: [e 64][c 128]
  const int b = blockIdx.x;          // 96 blocks: 3 taps x 32 e-tiles
  const int k = b >> 5, et = b & 31;
  const int e0 = et * 64;
  const int tid = threadIdx.x;
  const float* src = W1 + (size_t)k * 262144 + (size_t)e0 * 128;
#pragma unroll
  for (int i = 0; i < 8; ++i) {
    int idx4 = tid + i * 256;                       // 2048 float4s
    ((f32x4*)tile)[idx4] = ((const f32x4*)src)[idx4];
  }
  __syncthreads();
#pragma unroll
  for (int i = 0; i < 4; ++i) {
    int item = tid + i * 256;                       // 1024 items of 8 bf16
    int c = item >> 3, eo = (item & 7) * 8;
    union { unsigned short h[8]; uint4 v; } t;
#pragma unroll
    for (int u = 0; u < 8; ++u) t.h[u] = f2bf_r(tile[(eo + u) * 128 + c]);
    *(uint4*)(W1bt + (size_t)(k * 128 + c) * 2048 + e0 + eo) = t.v;
  }
}

// ---------- K0b: repack W2 [3,128,128] f32 -> W2t [j][d][c] bf16 (transposed) ----------
__global__ __launch_bounds__(256) void k_repack_w2(const float* __restrict__ W2,
                                                   unsigned short* __restrict__ W2t) {
  int idx = blockIdx.x * 256 + threadIdx.x;         // 49152
  int j = idx >> 14, r = idx & 16383, d = r >> 7, c = r & 127;
  W2t[idx] = f2bf_r(W2[(size_t)j * 16384 + (size_t)c * 128 + d]);
}

// ---------- K1: Y[N,384] = X[N,2048] @ W1bt^T, bf16 MFMA, fp32-A-in-LDS ----------
__global__ __launch_bounds__(256) void k_gemm1(const float* __restrict__ X,
                                               const unsigned short* __restrict__ Bt,
                                               float* __restrict__ Y) {
  __shared__ float Alds[128 * 32];          // 16 KB fp32 A tile [row][k]
  __shared__ unsigned short Blds[128 * 32]; // 8 KB bf16 B tile [col][k]
  const int bid = blockIdx.x;
  const int cb = bid % 3, rb = bid / 3;     // col-minor: siblings dispatch-adjacent for L2/LLC reuse
  const int row0 = rb * 128, col0 = cb * 128;
  const int tid = threadIdx.x, wave = tid >> 6, lane = tid & 63;
  const int mrow = lane & 15, quad = lane >> 4;

  // staging source pointers (advance by BK=32 each iter)
  const float* ag = X + (size_t)(row0 + wave * 8 + (lane >> 3)) * 2048 + (lane & 7) * 4;
  const unsigned short* bg = Bt + (size_t)(col0 + wave * 16 + (lane >> 2)) * 2048 + (lane & 3) * 8;

  const int wr = (wave >> 1) * 64, wc = (wave & 1) * 64;  // 2x2 wave grid, 64x64 each
  const float* aR = Alds + (wr + mrow) * 32 + quad * 8;
  const unsigned short* bR = Blds + (wc + mrow) * 32 + quad * 8;

  f32x4 acc[4][4] = {};

  for (int k0 = 0; k0 < 2048; k0 += 32) {
#pragma unroll
    for (int r = 0; r < 4; ++r)   // A: 4 rounds x 4KB (32 rows each)
      gl_lds16(ag + r * 65536, (char*)Alds + r * 4096 + wave * 1024);
#pragma unroll
    for (int r = 0; r < 2; ++r)   // B: 2 rounds x 4KB (64 cols each)
      gl_lds16(bg + (size_t)r * 131072, (char*)Blds + r * 4096 + wave * 1024);
    ag += 32; bg += 32;
    __syncthreads();              // drains vmcnt (global_load_lds) + barrier

    short8 af[4];
#pragma unroll
    for (int rt = 0; rt < 4; ++rt) {
      const f32x4* p = (const f32x4*)(aR + rt * 16 * 32);
      f32x4 x0 = p[0], x1 = p[1];           // A[m][quad*8 .. +8] fp32
      union { unsigned int u[4]; short8 s; } t;
      t.u[0] = pack2(x0[0], x0[1]); t.u[1] = pack2(x0[2], x0[3]);
      t.u[2] = pack2(x1[0], x1[1]); t.u[3] = pack2(x1[2], x1[3]);
      af[rt] = t.s;
    }
#pragma unroll
    for (int ct = 0; ct < 4; ++ct) {
      short8 bf = *(const short8*)(bR + ct * 16 * 32);
#pragma unroll
      for (int rt = 0; rt < 4; ++rt)
        acc[rt][ct] = MFMA16(af[rt], bf, acc[rt][ct]);
    }
    __syncthreads();
  }

  // epilogue: C layout col=lane&15, row=quad*4+reg
#pragma unroll
  for (int rt = 0; rt < 4; ++rt)
#pragma unroll
    for (int ct = 0; ct < 4; ++ct)
#pragma unroll
      for (int rg = 0; rg < 4; ++rg) {
        int rrow = row0 + wr + rt * 16 + quad * 4 + rg;
        int ccol = col0 + wc + ct * 16 + mrow;
        Y[(size_t)rrow * 384 + ccol] = acc[rt][ct][rg];
      }
}

// ---------- K2: tap-sum + tanh -> H (LDS bf16), 3 shifted GEMMs vs W2, log-softmax ----------
#define HS 136  // 128 + 8 pad (bank-conflict break)
__global__ __launch_bounds__(256) void k_stage2(const float* __restrict__ Y,
                                                const unsigned short* __restrict__ W2t,
                                                const float* __restrict__ b1,
                                                const float* __restrict__ b2,
                                                float* __restrict__ out) {
  __shared__ unsigned short Hlds[130 * HS];  // rows r0-2 .. r0+127
  __shared__ float zbuf[2][128];
  const int bid = blockIdx.x, tid = threadIdx.x;
  const int r0 = bid * 128;

  // H[p] = tanh( Y[p][c] + Y[p-1][128+c] + Y[p-2][256+c] + cnt*b1[c] )
  for (int idx = tid; idx < 130 * 128; idx += 256) {
    int hl = idx >> 7, c = idx & 127;
    int p = r0 - 2 + hl;
    float h = 0.f;
    if (p >= 0) {
      float s = Y[(size_t)p * 384 + c];
      float cnt = 1.f;
      if (p >= 1) { s += Y[(size_t)(p - 1) * 384 + 128 + c]; cnt += 1.f; }
      if (p >= 2) { s += Y[(size_t)(p - 2) * 384 + 256 + c]; cnt += 1.f; }
      h = tanhf(fmaf(cnt, b1[c], s));
    }
    Hlds[hl * HS + c] = f2bf_r(h);
  }
  __syncthreads();

  const int wave = tid >> 6, lane = tid & 63, mrow = lane & 15, quad = lane >> 4;
  f32x4 acc[2][8] = {};  // wave: 32 rows (2 rt) x 128 cols (8 ct)
#pragma unroll
  for (int j = 0; j < 3; ++j) {
#pragma unroll
    for (int kk = 0; kk < 4; ++kk) {
      short8 a0 = *(const short8*)&Hlds[(wave * 32 + mrow + j) * HS + kk * 32 + quad * 8];
      short8 a1 = *(const short8*)&Hlds[(wave * 32 + 16 + mrow + j) * HS + kk * 32 + quad * 8];
      const unsigned short* wp = W2t + (size_t)(j * 128 + mrow) * 128 + kk * 32 + quad * 8;
#pragma unroll
      for (int ct = 0; ct < 8; ++ct) {
        short8 bf = *(const short8*)(wp + ct * 16 * 128);  // L2-hot, same across blocks
        acc[0][ct] = MFMA16(a0, bf, acc[0][ct]);
        acc[1][ct] = MFMA16(a1, bf, acc[1][ct]);
      }
    }
  }

  // log-softmax per row; row's 128 cols live in 16 lanes (quad) x 8 ct-regs
#pragma unroll
  for (int rt = 0; rt < 2; ++rt) {
#pragma unroll
    for (int rg = 0; rg < 4; ++rg) {
      float z[8]; float m = -1e30f;
#pragma unroll
      for (int ct = 0; ct < 8; ++ct) {
        z[ct] = acc[rt][ct][rg] + 3.f * b2[ct * 16 + mrow];
        m = fmaxf(m, z[ct]);
      }
#pragma unroll
      for (int off = 1; off < 16; off <<= 1) m = fmaxf(m, __shfl_xor(m, off, 64));
      float s = 0.f;
#pragma unroll
      for (int ct = 0; ct < 8; ++ct) s += __expf(z[ct] - m);
#pragma unroll
      for (int off = 1; off < 16; off <<= 1) s += __shfl_xor(s, off, 64);
      float lse = m + __logf(s);
      int grow = r0 + wave * 32 + rt * 16 + quad * 4 + rg;
      if (grow >= 2) {
        float* op = out + (size_t)grow * 128 + mrow;
#pragma unroll
        for (int ct = 0; ct < 8; ++ct) op[ct * 16] = z[ct] - lse;
      }
    }
  }

  // fallback rows 0,1: Z0 = tanh(x@W1[0]+b1) @ W2[0] + b2, then log-softmax
  if (bid == 0) {
    __syncthreads();
    int row = tid >> 7, d = tid & 127;
    zbuf[row][d] = tanhf(Y[(size_t)row * 384 + d] + b1[d]);
    __syncthreads();
    float zv = b2[d];
    for (int c = 0; c < 128; ++c)
      zv = fmaf(zbuf[row][c], bf2f(W2t[(size_t)d * 128 + c]), zv);  // W2t[0][d][c] = W2[0][c][d]
    __syncthreads();
    zbuf[row][d] = zv;
    __syncthreads();
    float m = -1e30f;
    for (int c = 0; c < 128; ++c) m = fmaxf(m, zbuf[row][c]);
    float s = 0.f;
    for (int c = 0; c < 128; ++c) s += __expf(zbuf[row][c] - m);
    out[(size_t)row * 128 + d] = zv - m - __logf(s);
  }
}

// ---------- launch ----------
extern "C" void kernel_launch(void* const* d_in, const int* in_sizes, int n_in,
                              void* d_out, int out_size, void* d_ws, size_t ws_size,
                              hipStream_t stream) {
  const float* X  = (const float*)d_in[0];   // [32768, 1, 2048]
  const float* W1 = (const float*)d_in[1];   // [3, 2048, 128]
  const float* b1 = (const float*)d_in[2];   // [1, 128]
  const float* W2 = (const float*)d_in[3];   // [3, 128, 128]
  const float* b2 = (const float*)d_in[4];   // [1, 128]
  float* out = (float*)d_out;                // [32768, 1, 128] fp32

  // workspace layout (~52 MB total)
  float* Y = (float*)d_ws;                                              // 32768*384*4 = 50,331,648
  unsigned short* W1bt = (unsigned short*)((char*)d_ws + 50331648);     // 384*2048*2  = 1,572,864
  unsigned short* W2t  = (unsigned short*)((char*)d_ws + 50331648 + 1572864); // 98,304

  k_repack_w1<<<96, 256, 0, stream>>>(W1, W1bt);
  k_repack_w2<<<192, 256, 0, stream>>>(W2, W2t);
  k_gemm1<<<768, 256, 0, stream>>>(X, W1bt, Y);
  k_stage2<<<256, 256, 0, stream>>>(Y, W2t, b1, b2, out);
}

// Round 2
// 469.204 us; speedup vs baseline: 1.1268x; 1.1268x over previous
//
#include <hip/hip_runtime.h>
#include <math.h>

// ---------- types / helpers ----------
typedef __attribute__((ext_vector_type(8))) short short8;   // 8 bf16 (4 VGPRs)
typedef __attribute__((ext_vector_type(4))) float f32x4;    // MFMA acc

#define MFMA16(a, b, c) __builtin_amdgcn_mfma_f32_16x16x32_bf16((a), (b), (c), 0, 0, 0)

// async global->LDS, 16B per lane. LDS dest is wave-uniform base + lane*16;
// the GLOBAL source address is per-lane -> we can swizzle the source freely.
__device__ inline void gl_lds16(const void* g, void* l) {
  __builtin_amdgcn_global_load_lds(
      (const __attribute__((address_space(1))) void*)g,
      (__attribute__((address_space(3))) void*)l, 16, 0, 0);
}

// pack two f32 -> two bf16 (truncation; error << 0.2475 threshold, verified R1)
__device__ inline unsigned int pack2(float lo, float hi) {
  unsigned int ulo = __float_as_uint(lo), uhi = __float_as_uint(hi);
  return (uhi & 0xFFFF0000u) | (ulo >> 16);
}
// round-to-nearest (ties up) f32 -> bf16
__device__ inline unsigned short f2bf_r(float f) {
  return (unsigned short)((__float_as_uint(f) + 0x8000u) >> 16);
}
__device__ inline float bf2f(unsigned short h) {
  return __uint_as_float(((unsigned int)h) << 16);
}

// ---------- K0: repack W1 [3,2048,128] f32 -> W1bt [384,2048] bf16 (B^T, k-contiguous) ----------
__global__ __launch_bounds__(256) void k_repack_w1(const float* __restrict__ W1,
                                                   unsigned short* __restrict__ W1bt) {
  __shared__ float tile[64 * 128];   // 32 KB: [e 64][c 128]
  const int b = blockIdx.x;          // 96 blocks: 3 taps x 32 e-tiles
  const int k = b >> 5, et = b & 31;
  const int e0 = et * 64;
  const int tid = threadIdx.x;
  const float* src = W1 + (size_t)k * 262144 + (size_t)e0 * 128;
#pragma unroll
  for (int i = 0; i < 8; ++i) {
    int idx4 = tid + i * 256;                       // 2048 float4s
    ((f32x4*)tile)[idx4] = ((const f32x4*)src)[idx4];
  }
  __syncthreads();
#pragma unroll
  for (int i = 0; i < 4; ++i) {
    int item = tid + i * 256;                       // 1024 items of 8 bf16
    int c = item >> 3, eo = (item & 7) * 8;
    union { unsigned short h[8]; uint4 v; } t;
#pragma unroll
    for (int u = 0; u < 8; ++u) t.h[u] = f2bf_r(tile[(eo + u) * 128 + c]);
    *(uint4*)(W1bt + (size_t)(k * 128 + c) * 2048 + e0 + eo) = t.v;
  }
}

// ---------- K0b: repack W2 [3,128,128] f32 -> W2t [j][d][c] bf16 (transposed) ----------
__global__ __launch_bounds__(256) void k_repack_w2(const float* __restrict__ W2,
                                                   unsigned short* __restrict__ W2t) {
  int idx = blockIdx.x * 256 + threadIdx.x;         // 49152
  int j = idx >> 14, r = idx & 16383, d = r >> 7, c = r & 127;
  W2t[idx] = f2bf_r(W2[(size_t)j * 16384 + (size_t)c * 128 + d]);
}

// ---------- K1: Y[N,384] = X[N,2048] @ W1bt^T ----------
// BK=64, chunk-XOR-swizzled LDS (conflict-free ds_read_b128), XCD-aware mapping.
__global__ __launch_bounds__(256, 3) void k_gemm1(const float* __restrict__ X,
                                                  const unsigned short* __restrict__ Bt,
                                                  float* __restrict__ Y) {
  __shared__ float Alds[128 * 64];           // 32 KB fp32; chunk c stored at c^(row&15)
  __shared__ unsigned short Blds[128 * 64];  // 16 KB bf16; chunk c stored at c^(col&7)

  // XCD swizzle: 3 col-siblings of one row-block sit 8 apart -> same XCD (rr dispatch)
  const int g = blockIdx.x;
  const int grp = g / 24, within = g % 24;
  const int cb = within >> 3, rb = grp * 8 + (within & 7);
  const int row0 = rb * 128, col0 = cb * 128;

  const int tid = threadIdx.x, wave = tid >> 6, lane = tid & 63;
  const int mrow = lane & 15, quad = lane >> 4;

  // per-call swizzled staging source pointers (advance by 64 elems per iter)
  const float* agp[8];
#pragma unroll
  for (int r = 0; r < 8; ++r) {
    int row = wave * 32 + r * 4 + (lane >> 4);      // 4 rows per call
    int c = (lane & 15) ^ (row & 15);               // 16B chunk swizzle
    agp[r] = X + (size_t)(row0 + row) * 2048 + c * 4;
  }
  const unsigned short* bgp[4];
#pragma unroll
  for (int r = 0; r < 4; ++r) {
    int col = wave * 32 + r * 8 + (lane >> 3);      // 8 cols per call
    int c = (lane & 7) ^ (col & 7);
    bgp[r] = Bt + (size_t)(col0 + col) * 2048 + c * 8;
  }

  const int wr = (wave >> 1) * 64, wc = (wave & 1) * 64;  // 2x2 wave grid, 64x64

  f32x4 acc[4][4] = {};

  for (int k0 = 0; k0 < 2048; k0 += 64) {
#pragma unroll
    for (int r = 0; r < 8; ++r)
      gl_lds16(agp[r], (char*)Alds + (wave * 32 + r * 4) * 256);
#pragma unroll
    for (int r = 0; r < 4; ++r)
      gl_lds16(bgp[r], (char*)Blds + (wave * 32 + r * 8) * 128);
#pragma unroll
    for (int r = 0; r < 8; ++r) agp[r] += 64;
#pragma unroll
    for (int r = 0; r < 4; ++r) bgp[r] += 64;
    __syncthreads();   // drains vmcnt(0) + barrier

#pragma unroll
    for (int s = 0; s < 2; ++s) {
      short8 af[4];
#pragma unroll
      for (int rt = 0; rt < 4; ++rt) {
        int row = wr + rt * 16 + mrow;
        int c0 = s * 8 + quad * 2;
        const float* base = Alds + row * 64;
        f32x4 x0 = *(const f32x4*)(base + ((c0 ^ (row & 15)) * 4));
        f32x4 x1 = *(const f32x4*)(base + (((c0 + 1) ^ (row & 15)) * 4));
        union { unsigned int u[4]; short8 v; } t;
        t.u[0] = pack2(x0[0], x0[1]); t.u[1] = pack2(x0[2], x0[3]);
        t.u[2] = pack2(x1[0], x1[1]); t.u[3] = pack2(x1[2], x1[3]);
        af[rt] = t.v;
      }
#pragma unroll
      for (int ct = 0; ct < 4; ++ct) {
        int col = wc + ct * 16 + mrow;
        int ch = (s * 4 + quad) ^ (col & 7);
        short8 bf = *(const short8*)(Blds + col * 64 + ch * 8);
#pragma unroll
        for (int rt = 0; rt < 4; ++rt)
          acc[rt][ct] = MFMA16(af[rt], bf, acc[rt][ct]);
      }
    }
    __syncthreads();
  }

  // epilogue: C layout col=lane&15, row=quad*4+reg (verified R1)
#pragma unroll
  for (int rt = 0; rt < 4; ++rt)
#pragma unroll
    for (int ct = 0; ct < 4; ++ct)
#pragma unroll
      for (int rg = 0; rg < 4; ++rg) {
        int rrow = row0 + wr + rt * 16 + quad * 4 + rg;
        int ccol = col0 + wc + ct * 16 + mrow;
        Y[(size_t)rrow * 384 + ccol] = acc[rt][ct][rg];
      }
}

// ---------- K2: tap-sum + tanh -> H (LDS bf16), 3 shifted GEMMs vs W2, log-softmax ----------
// 64-row blocks (512 blocks = 2/CU) for latency hiding.
#define HS 136  // 128 + 8 pad -> row stride 272 B == 4 banks shift: conflict-free frag reads
__global__ __launch_bounds__(256) void k_stage2(const float* __restrict__ Y,
                                                const unsigned short* __restrict__ W2t,
                                                const float* __restrict__ b1,
                                                const float* __restrict__ b2,
                                                float* __restrict__ out) {
  __shared__ unsigned short Hlds[66 * HS];  // rows r0-2 .. r0+63
  __shared__ float zbuf[2][128];
  const int bid = blockIdx.x, tid = threadIdx.x;
  const int r0 = bid * 64;

  // H[p] = tanh( Y[p][c] + Y[p-1][128+c] + Y[p-2][256+c] + cnt*b1[c] )
  for (int idx = tid; idx < 66 * 128; idx += 256) {
    int hl = idx >> 7, c = idx & 127;
    int p = r0 - 2 + hl;
    float h = 0.f;
    if (p >= 0) {
      float s = Y[(size_t)p * 384 + c];
      float cnt = 1.f;
      if (p >= 1) { s += Y[(size_t)(p - 1) * 384 + 128 + c]; cnt += 1.f; }
      if (p >= 2) { s += Y[(size_t)(p - 2) * 384 + 256 + c]; cnt += 1.f; }
      h = tanhf(fmaf(cnt, b1[c], s));
    }
    Hlds[hl * HS + c] = f2bf_r(h);
  }
  __syncthreads();

  const int wave = tid >> 6, lane = tid & 63, mrow = lane & 15, quad = lane >> 4;
  f32x4 acc[8] = {};  // wave: 16 rows x 128 cols (8 ct tiles)
#pragma unroll
  for (int j = 0; j < 3; ++j) {
#pragma unroll
    for (int kk = 0; kk < 4; ++kk) {
      short8 a0 = *(const short8*)&Hlds[(wave * 16 + mrow + j) * HS + kk * 32 + quad * 8];
      const unsigned short* wp = W2t + (size_t)(j * 128 + mrow) * 128 + kk * 32 + quad * 8;
#pragma unroll
      for (int ct = 0; ct < 8; ++ct)
        acc[ct] = MFMA16(a0, *(const short8*)(wp + ct * 16 * 128), acc[ct]);
    }
  }

  // log-softmax per row; row's 128 cols live in 16 lanes (mrow) x 8 ct-regs
#pragma unroll
  for (int rg = 0; rg < 4; ++rg) {
    float z[8]; float m = -1e30f;
#pragma unroll
    for (int ct = 0; ct < 8; ++ct) {
      z[ct] = acc[ct][rg] + 3.f * b2[ct * 16 + mrow];
      m = fmaxf(m, z[ct]);
    }
#pragma unroll
    for (int off = 1; off < 16; off <<= 1) m = fmaxf(m, __shfl_xor(m, off, 64));
    float s = 0.f;
#pragma unroll
    for (int ct = 0; ct < 8; ++ct) s += __expf(z[ct] - m);
#pragma unroll
    for (int off = 1; off < 16; off <<= 1) s += __shfl_xor(s, off, 64);
    float lse = m + __logf(s);
    int grow = r0 + wave * 16 + quad * 4 + rg;
    if (grow >= 2) {
      float* op = out + (size_t)grow * 128 + mrow;
#pragma unroll
      for (int ct = 0; ct < 8; ++ct) op[ct * 16] = z[ct] - lse;
    }
  }

  // fallback rows 0,1: Z0 = tanh(x@W1[0]+b1) @ W2[0] + b2, then log-softmax
  if (bid == 0) {
    __syncthreads();
    int row = tid >> 7, d = tid & 127;
    zbuf[row][d] = tanhf(Y[(size_t)row * 384 + d] + b1[d]);
    __syncthreads();
    float zv = b2[d];
    for (int c = 0; c < 128; ++c)
      zv = fmaf(zbuf[row][c], bf2f(W2t[(size_t)d * 128 + c]), zv);  // W2t[0][d][c] = W2[0][c][d]
    __syncthreads();
    zbuf[row][d] = zv;
    __syncthreads();
    float m = -1e30f;
    for (int c = 0; c < 128; ++c) m = fmaxf(m, zbuf[row][c]);
    float s = 0.f;
    for (int c = 0; c < 128; ++c) s += __expf(zbuf[row][c] - m);
    out[(size_t)row * 128 + d] = zv - m - __logf(s);
  }
}

// ---------- launch ----------
extern "C" void kernel_launch(void* const* d_in, const int* in_sizes, int n_in,
                              void* d_out, int out_size, void* d_ws, size_t ws_size,
                              hipStream_t stream) {
  const float* X  = (const float*)d_in[0];   // [32768, 1, 2048]
  const float* W1 = (const float*)d_in[1];   // [3, 2048, 128]
  const float* b1 = (const float*)d_in[2];   // [1, 128]
  const float* W2 = (const float*)d_in[3];   // [3, 128, 128]
  const float* b2 = (const float*)d_in[4];   // [1, 128]
  float* out = (float*)d_out;                // [32768, 1, 128] fp32

  // workspace layout (~52 MB total)
  float* Y = (float*)d_ws;                                              // 32768*384*4 = 50,331,648
  unsigned short* W1bt = (unsigned short*)((char*)d_ws + 50331648);     // 384*2048*2  = 1,572,864
  unsigned short* W2t  = (unsigned short*)((char*)d_ws + 50331648 + 1572864); // 98,304

  k_repack_w1<<<96, 256, 0, stream>>>(W1, W1bt);
  k_repack_w2<<<192, 256, 0, stream>>>(W2, W2t);
  k_gemm1<<<768, 256, 0, stream>>>(X, W1bt, Y);
  k_stage2<<<512, 256, 0, stream>>>(Y, W2t, b1, b2, out);
}

// Round 3
// 460.523 us; speedup vs baseline: 1.1481x; 1.0189x over previous
//
#include <hip/hip_runtime.h>
#include <math.h>

// ---------- types / helpers ----------
typedef __attribute__((ext_vector_type(8))) short short8;   // 8 bf16 (4 VGPRs)
typedef __attribute__((ext_vector_type(4))) float f32x4;    // MFMA acc

#define MFMA16(a, b, c) __builtin_amdgcn_mfma_f32_16x16x32_bf16((a), (b), (c), 0, 0, 0)

// async global->LDS, 16B per lane. LDS dest is wave-uniform base + lane*16;
// the GLOBAL source address is per-lane -> swizzle the source for free.
__device__ inline void gl_lds16(const void* g, void* l) {
  __builtin_amdgcn_global_load_lds(
      (const __attribute__((address_space(1))) void*)g,
      (__attribute__((address_space(3))) void*)l, 16, 0, 0);
}

// pack two f32 -> two bf16 (truncation; error budget verified R1/R2)
__device__ inline unsigned int pack2(float lo, float hi) {
  unsigned int ulo = __float_as_uint(lo), uhi = __float_as_uint(hi);
  return (uhi & 0xFFFF0000u) | (ulo >> 16);
}
// round-to-nearest f32 -> bf16
__device__ inline unsigned short f2bf_r(float f) {
  return (unsigned short)((__float_as_uint(f) + 0x8000u) >> 16);
}
__device__ inline float bf2f(unsigned short h) {
  return __uint_as_float(((unsigned int)h) << 16);
}

// ---------- K0: repack W1 [3,2048,128] f32 -> W1bt [384,2048] bf16 (B^T, k-contiguous) ----------
__global__ __launch_bounds__(256) void k_repack_w1(const float* __restrict__ W1,
                                                   unsigned short* __restrict__ W1bt) {
  __shared__ float tile[64 * 128];   // 32 KB: [e 64][c 128]
  const int b = blockIdx.x;          // 96 blocks: 3 taps x 32 e-tiles
  const int k = b >> 5, et = b & 31;
  const int e0 = et * 64;
  const int tid = threadIdx.x;
  const float* src = W1 + (size_t)k * 262144 + (size_t)e0 * 128;
#pragma unroll
  for (int i = 0; i < 8; ++i) {
    int idx4 = tid + i * 256;                       // 2048 float4s
    ((f32x4*)tile)[idx4] = ((const f32x4*)src)[idx4];
  }
  __syncthreads();
#pragma unroll
  for (int i = 0; i < 4; ++i) {
    int item = tid + i * 256;                       // 1024 items of 8 bf16
    int c = item >> 3, eo = (item & 7) * 8;
    union { unsigned short h[8]; uint4 v; } t;
#pragma unroll
    for (int u = 0; u < 8; ++u) t.h[u] = f2bf_r(tile[(eo + u) * 128 + c]);
    *(uint4*)(W1bt + (size_t)(k * 128 + c) * 2048 + e0 + eo) = t.v;
  }
}

// ---------- K0b: repack W2 [3,128,128] f32 -> W2t [j][d][c] bf16 (transposed) ----------
__global__ __launch_bounds__(256) void k_repack_w2(const float* __restrict__ W2,
                                                   unsigned short* __restrict__ W2t) {
  int idx = blockIdx.x * 256 + threadIdx.x;         // 49152
  int j = idx >> 14, r = idx & 16383, d = r >> 7, c = r & 127;
  W2t[idx] = f2bf_r(W2[(size_t)j * 16384 + (size_t)c * 128 + d]);
}

// ---------- K1: Ybf[N,384] = X[N,2048] @ W1bt^T, bf16 out ----------
// BM=64 x BN=384 (full width: X read exactly once per block) x BK=64.
// 512 blocks, 2 blocks/CU (LDS 64KB, ~170 VGPR). Swizzled LDS, conflict-free.
__global__ __launch_bounds__(256, 2) void k_gemm1(const float* __restrict__ X,
                                                  const unsigned short* __restrict__ Bt,
                                                  unsigned short* __restrict__ Ybf) {
  __shared__ float Alds[64 * 64];            // 16 KB fp32; row stride 256B (16 chunks), chunk c at c^(row&15)
  __shared__ unsigned short Blds[384 * 64];  // 48 KB bf16; row stride 128B (8 chunks),  chunk c at c^(col&7)

  const int r0 = blockIdx.x * 64;
  const int tid = threadIdx.x, wave = tid >> 6, lane = tid & 63;
  const int mrow = lane & 15, quad = lane >> 4;

  // staging source pointers (advance 64 elems/iter)
  const float* agp[4];
#pragma unroll
  for (int r = 0; r < 4; ++r) {
    int row = wave * 16 + r * 4 + (lane >> 4);       // 4 rows per call
    int c = (lane & 15) ^ (row & 15);
    agp[r] = X + (size_t)(r0 + row) * 2048 + c * 4;
  }
  const unsigned short* bgp[12];
#pragma unroll
  for (int r = 0; r < 12; ++r) {
    int col = wave * 96 + r * 8 + (lane >> 3);       // 8 cols per call
    int c = (lane & 7) ^ (col & 7);
    bgp[r] = Bt + (size_t)col * 2048 + c * 8;
  }

  f32x4 acc[4][6] = {};   // wave: 64 rows (4 rt) x 96 cols (6 ct)

  for (int k0 = 0; k0 < 2048; k0 += 64) {
#pragma unroll
    for (int r = 0; r < 4; ++r)
      gl_lds16(agp[r], (char*)Alds + (wave * 16 + r * 4) * 256);
#pragma unroll
    for (int r = 0; r < 12; ++r)
      gl_lds16(bgp[r], (char*)Blds + (wave * 96 + r * 8) * 128);
#pragma unroll
    for (int r = 0; r < 4; ++r) agp[r] += 64;
#pragma unroll
    for (int r = 0; r < 12; ++r) bgp[r] += 64;
    __syncthreads();   // drains vmcnt(0) + barrier

#pragma unroll
    for (int s = 0; s < 2; ++s) {
      short8 af[4];
#pragma unroll
      for (int rt = 0; rt < 4; ++rt) {
        int row = rt * 16 + mrow;                    // row&15 == mrow
        int c0 = s * 8 + quad * 2;
        const float* base = Alds + row * 64;
        f32x4 x0 = *(const f32x4*)(base + ((c0 ^ mrow) * 4));
        f32x4 x1 = *(const f32x4*)(base + (((c0 + 1) ^ mrow) * 4));
        union { unsigned int u[4]; short8 v; } t;
        t.u[0] = pack2(x0[0], x0[1]); t.u[1] = pack2(x0[2], x0[3]);
        t.u[2] = pack2(x1[0], x1[1]); t.u[3] = pack2(x1[2], x1[3]);
        af[rt] = t.v;
      }
#pragma unroll
      for (int ct = 0; ct < 6; ++ct) {
        int col = wave * 96 + ct * 16 + mrow;        // col&7 == mrow&7
        int ch = (s * 4 + quad) ^ (mrow & 7);
        short8 bf = *(const short8*)(Blds + col * 64 + ch * 8);
#pragma unroll
        for (int rt = 0; rt < 4; ++rt)
          acc[rt][ct] = MFMA16(af[rt], bf, acc[rt][ct]);
      }
    }
    __syncthreads();
  }

  // epilogue: C layout col=lane&15, row=quad*4+reg; store bf16 (L2 merges 32B runs)
#pragma unroll
  for (int rt = 0; rt < 4; ++rt)
#pragma unroll
    for (int ct = 0; ct < 6; ++ct)
#pragma unroll
      for (int rg = 0; rg < 4; ++rg) {
        int rrow = r0 + rt * 16 + quad * 4 + rg;
        int ccol = wave * 96 + ct * 16 + mrow;
        Ybf[(size_t)rrow * 384 + ccol] = f2bf_r(acc[rt][ct][rg]);
      }
}

// ---------- K2: tap-sum + tanh -> H (LDS bf16), 3 shifted GEMMs vs W2, log-softmax ----------
#define HS 136  // 128 + 8 pad
__global__ __launch_bounds__(256) void k_stage2(const unsigned short* __restrict__ Yb,
                                                const unsigned short* __restrict__ W2t,
                                                const float* __restrict__ b1,
                                                const float* __restrict__ b2,
                                                float* __restrict__ out) {
  __shared__ unsigned short Hlds[66 * HS];  // rows r0-2 .. r0+63
  __shared__ float zbuf[2][128];
  const int bid = blockIdx.x, tid = threadIdx.x;
  const int r0 = bid * 64;

  // H[p] = tanh( Y[p][c] + Y[p-1][128+c] + Y[p-2][256+c] + cnt*b1[c] )
  for (int idx = tid; idx < 66 * 128; idx += 256) {
    int hl = idx >> 7, c = idx & 127;
    int p = r0 - 2 + hl;
    float h = 0.f;
    if (p >= 0) {
      float s = bf2f(Yb[(size_t)p * 384 + c]);
      float cnt = 1.f;
      if (p >= 1) { s += bf2f(Yb[(size_t)(p - 1) * 384 + 128 + c]); cnt += 1.f; }
      if (p >= 2) { s += bf2f(Yb[(size_t)(p - 2) * 384 + 256 + c]); cnt += 1.f; }
      h = tanhf(fmaf(cnt, b1[c], s));
    }
    Hlds[hl * HS + c] = f2bf_r(h);
  }
  __syncthreads();

  const int wave = tid >> 6, lane = tid & 63, mrow = lane & 15, quad = lane >> 4;
  f32x4 acc[8] = {};  // wave: 16 rows x 128 cols (8 ct tiles)
#pragma unroll
  for (int j = 0; j < 3; ++j) {
#pragma unroll
    for (int kk = 0; kk < 4; ++kk) {
      short8 a0 = *(const short8*)&Hlds[(wave * 16 + mrow + j) * HS + kk * 32 + quad * 8];
      const unsigned short* wp = W2t + (size_t)(j * 128 + mrow) * 128 + kk * 32 + quad * 8;
#pragma unroll
      for (int ct = 0; ct < 8; ++ct)
        acc[ct] = MFMA16(a0, *(const short8*)(wp + ct * 16 * 128), acc[ct]);
    }
  }

  // log-softmax per row; row's 128 cols live in 16 lanes (mrow) x 8 ct-regs
#pragma unroll
  for (int rg = 0; rg < 4; ++rg) {
    float z[8]; float m = -1e30f;
#pragma unroll
    for (int ct = 0; ct < 8; ++ct) {
      z[ct] = acc[ct][rg] + 3.f * b2[ct * 16 + mrow];
      m = fmaxf(m, z[ct]);
    }
#pragma unroll
    for (int off = 1; off < 16; off <<= 1) m = fmaxf(m, __shfl_xor(m, off, 64));
    float s = 0.f;
#pragma unroll
    for (int ct = 0; ct < 8; ++ct) s += __expf(z[ct] - m);
#pragma unroll
    for (int off = 1; off < 16; off <<= 1) s += __shfl_xor(s, off, 64);
    float lse = m + __logf(s);
    int grow = r0 + wave * 16 + quad * 4 + rg;
    if (grow >= 2) {
      float* op = out + (size_t)grow * 128 + mrow;
#pragma unroll
      for (int ct = 0; ct < 8; ++ct) op[ct * 16] = z[ct] - lse;
    }
  }

  // fallback rows 0,1: Z0 = tanh(x@W1[0]+b1) @ W2[0] + b2, then log-softmax
  if (bid == 0) {
    __syncthreads();
    int row = tid >> 7, d = tid & 127;
    zbuf[row][d] = tanhf(bf2f(Yb[(size_t)row * 384 + d]) + b1[d]);
    __syncthreads();
    float zv = b2[d];
    for (int c = 0; c < 128; ++c)
      zv = fmaf(zbuf[row][c], bf2f(W2t[(size_t)d * 128 + c]), zv);  // W2t[0][d][c] = W2[0][c][d]
    __syncthreads();
    zbuf[row][d] = zv;
    __syncthreads();
    float m = -1e30f;
    for (int c = 0; c < 128; ++c) m = fmaxf(m, zbuf[row][c]);
    float s = 0.f;
    for (int c = 0; c < 128; ++c) s += __expf(zbuf[row][c] - m);
    out[(size_t)row * 128 + d] = zv - m - __logf(s);
  }
}

// ---------- launch ----------
extern "C" void kernel_launch(void* const* d_in, const int* in_sizes, int n_in,
                              void* d_out, int out_size, void* d_ws, size_t ws_size,
                              hipStream_t stream) {
  const float* X  = (const float*)d_in[0];   // [32768, 1, 2048]
  const float* W1 = (const float*)d_in[1];   // [3, 2048, 128]
  const float* b1 = (const float*)d_in[2];   // [1, 128]
  const float* W2 = (const float*)d_in[3];   // [3, 128, 128]
  const float* b2 = (const float*)d_in[4];   // [1, 128]
  float* out = (float*)d_out;                // [32768, 1, 128] fp32

  // workspace layout (~27 MB total)
  unsigned short* Ybf  = (unsigned short*)d_ws;                          // 32768*384*2 = 25,165,824
  unsigned short* W1bt = (unsigned short*)((char*)d_ws + 25165824);      // 384*2048*2  = 1,572,864
  unsigned short* W2t  = (unsigned short*)((char*)d_ws + 25165824 + 1572864); // 98,304

  k_repack_w1<<<96, 256, 0, stream>>>(W1, W1bt);
  k_repack_w2<<<192, 256, 0, stream>>>(W2, W2t);
  k_gemm1<<<512, 256, 0, stream>>>(X, W1bt, Ybf);
  k_stage2<<<512, 256, 0, stream>>>(Ybf, W2t, b1, b2, out);
}

// Round 4
// 425.367 us; speedup vs baseline: 1.2430x; 1.0826x over previous
//
#include <hip/hip_runtime.h>
#include <math.h>

// ---------- types / helpers ----------
typedef __attribute__((ext_vector_type(8))) short short8;   // 8 bf16 (4 VGPRs)
typedef __attribute__((ext_vector_type(4))) float f32x4;    // MFMA acc

#define MFMA16(a, b, c) __builtin_amdgcn_mfma_f32_16x16x32_bf16((a), (b), (c), 0, 0, 0)

// async global->LDS, 16B per lane. LDS dest is wave-uniform base + lane*16;
// the GLOBAL source address is per-lane -> swizzle the source for free.
__device__ inline void gl_lds16(const void* g, void* l) {
  __builtin_amdgcn_global_load_lds(
      (const __attribute__((address_space(1))) void*)g,
      (__attribute__((address_space(3))) void*)l, 16, 0, 0);
}

__device__ inline unsigned int pack2(float lo, float hi) {
  unsigned int ulo = __float_as_uint(lo), uhi = __float_as_uint(hi);
  return (uhi & 0xFFFF0000u) | (ulo >> 16);
}
__device__ inline unsigned short f2bf_r(float f) {
  return (unsigned short)((__float_as_uint(f) + 0x8000u) >> 16);
}
__device__ inline float bf2f(unsigned short h) {
  return __uint_as_float(((unsigned int)h) << 16);
}

// ---------- K0: merged weight repack ----------
// blocks 0..95:   W1 [3,2048,128] f32 -> W1bt [384,2048] bf16 (B^T, k-contiguous)
// blocks 96..287: W2 [3,128,128] f32  -> W2t  [j][d][c]  bf16 (transposed)
__global__ __launch_bounds__(256) void k_repack(const float* __restrict__ W1,
                                                const float* __restrict__ W2,
                                                unsigned short* __restrict__ W1bt,
                                                unsigned short* __restrict__ W2t) {
  __shared__ float tile[64 * 128];   // 32 KB
  const int b = blockIdx.x, tid = threadIdx.x;
  if (b < 96) {
    const int k = b >> 5, et = b & 31;
    const int e0 = et * 64;
    const float* src = W1 + (size_t)k * 262144 + (size_t)e0 * 128;
#pragma unroll
    for (int i = 0; i < 8; ++i) {
      int idx4 = tid + i * 256;
      ((f32x4*)tile)[idx4] = ((const f32x4*)src)[idx4];
    }
    __syncthreads();
#pragma unroll
    for (int i = 0; i < 4; ++i) {
      int item = tid + i * 256;
      int c = item >> 3, eo = (item & 7) * 8;
      union { unsigned short h[8]; uint4 v; } t;
#pragma unroll
      for (int u = 0; u < 8; ++u) t.h[u] = f2bf_r(tile[(eo + u) * 128 + c]);
      *(uint4*)(W1bt + (size_t)(k * 128 + c) * 2048 + e0 + eo) = t.v;
    }
  } else {
    int idx = (b - 96) * 256 + tid;                 // 49152
    int j = idx >> 14, r = idx & 16383, d = r >> 7, c = r & 127;
    W2t[idx] = f2bf_r(W2[(size_t)j * 16384 + (size_t)c * 128 + d]);
  }
}

// ---------- K1: fully fused stage1 GEMM + tap-sum/tanh + stage2 GEMM + log-softmax ----------
// 512 blocks x 64 out rows. Stage-1 computes rows r0-4..r0+63 (68 staged, 80 logical).
__global__ __launch_bounds__(256, 2) void k_fused(const float* __restrict__ X,
                                                  const unsigned short* __restrict__ Bt,
                                                  const unsigned short* __restrict__ W2t,
                                                  const float* __restrict__ b1,
                                                  const float* __restrict__ b2,
                                                  float* __restrict__ out) {
  __shared__ __align__(16) char smem[66560];
  float* Alds = (float*)smem;                             // 68 rows x 256B, chunk c at c^(i&15)
  unsigned short* Blds = (unsigned short*)(smem + 17408); // 384 cols x 128B, chunk c at c^(col&7)
  unsigned short* Yt = (unsigned short*)smem;             // phase B: 80 x 392 bf16 (62,720 B)
  float* zbuf = (float*)(smem + 62720);                   // 2 x 128 f32

  const int r0 = blockIdx.x * 64;
  const int tid = threadIdx.x, wave = tid >> 6, lane = tid & 63;
  const int mrow = lane & 15, quad = lane >> 4;

  // ---- stage-1 staging pointers: Alds row i <-> X row r0-4+i (clamped) ----
  const float* agp[5];
#pragma unroll
  for (int r = 0; r < 4; ++r) {
    int i = wave * 16 + r * 4 + (lane >> 4);
    int g = r0 - 4 + i; if (g < 0) g = 0;             // block 0 halo clamp (masked later)
    int c = (lane & 15) ^ (i & 15);
    agp[r] = X + (size_t)g * 2048 + c * 4;
  }
  {
    int i = 64 + (lane >> 4);                         // wave-0 extra: rows 64..67
    int c = (lane & 15) ^ (i & 15);
    agp[4] = X + (size_t)(r0 - 4 + i) * 2048 + c * 4;
  }
  const unsigned short* bgp[12];
#pragma unroll
  for (int r = 0; r < 12; ++r) {
    int col = wave * 96 + r * 8 + (lane >> 3);
    int c = (lane & 7) ^ (col & 7);
    bgp[r] = Bt + (size_t)col * 2048 + c * 8;
  }

  f32x4 acc[5][6] = {};   // wave: 80 logical rows (5 rt) x 96 cols (6 ct)

  for (int k0 = 0; k0 < 2048; k0 += 64) {
#pragma unroll
    for (int r = 0; r < 4; ++r)
      gl_lds16(agp[r], (char*)Alds + (wave * 16 + r * 4) * 256);
    if (wave == 0) gl_lds16(agp[4], (char*)Alds + 64 * 256);
#pragma unroll
    for (int r = 0; r < 12; ++r)
      gl_lds16(bgp[r], (char*)Blds + (wave * 96 + r * 8) * 128);
#pragma unroll
    for (int r = 0; r < 5; ++r) agp[r] += 64;
#pragma unroll
    for (int r = 0; r < 12; ++r) bgp[r] += 64;
    __syncthreads();   // drains vmcnt(0) + barrier

#pragma unroll
    for (int s = 0; s < 2; ++s) {
      short8 af[5];
#pragma unroll
      for (int rt = 0; rt < 5; ++rt) {                // rt=4 rows 68..79 read garbage (unused)
        int row = rt * 16 + mrow;
        int c0 = s * 8 + quad * 2;
        const float* base = Alds + row * 64;
        f32x4 x0 = *(const f32x4*)(base + ((c0 ^ mrow) * 4));
        f32x4 x1 = *(const f32x4*)(base + (((c0 + 1) ^ mrow) * 4));
        union { unsigned int u[4]; short8 v; } t;
        t.u[0] = pack2(x0[0], x0[1]); t.u[1] = pack2(x0[2], x0[3]);
        t.u[2] = pack2(x1[0], x1[1]); t.u[3] = pack2(x1[2], x1[3]);
        af[rt] = t.v;
      }
#pragma unroll
      for (int ct = 0; ct < 6; ++ct) {
        int col = wave * 96 + ct * 16 + mrow;
        int ch = (s * 4 + quad) ^ (mrow & 7);
        short8 bf = *(const short8*)(Blds + col * 64 + ch * 8);
#pragma unroll
        for (int rt = 0; rt < 5; ++rt)
          acc[rt][ct] = MFMA16(af[rt], bf, acc[rt][ct]);
      }
    }
    __syncthreads();
  }

  // ---- spill acc -> Yt (bf16). Yt row i <-> Y global row r0-4+i; stride 392 (4-bank shift) ----
#pragma unroll
  for (int rt = 0; rt < 5; ++rt)
#pragma unroll
    for (int ct = 0; ct < 6; ++ct)
#pragma unroll
      for (int rg = 0; rg < 4; ++rg) {
        int l = rt * 16 + quad * 4 + rg;
        int col = wave * 96 + ct * 16 + mrow;
        Yt[l * 392 + col] = f2bf_r(acc[rt][ct][rg]);
      }
  __syncthreads();

  // ---- H[p]=tanh(sum taps + cnt*b1), p in [r0-2, r0+63]; store in-place at dead tap-2 slot ----
  // H[p] slot = Yt[p-r0+2][256+c]. Self-RMW per element: race-free (blk0/blk1 never written).
  for (int idx = tid; idx < 66 * 128; idx += 256) {
    int hl = idx >> 7, c = idx & 127;
    int p = r0 - 2 + hl;
    int i = hl + 2;                                   // tap-0 Yt row
    float h = 0.f;
    if (p >= 0) {
      float s = bf2f(Yt[i * 392 + c]);
      float cnt = 1.f;
      if (p >= 1) { s += bf2f(Yt[(i - 1) * 392 + 128 + c]); cnt += 1.f; }
      if (p >= 2) { s += bf2f(Yt[(i - 2) * 392 + 256 + c]); cnt += 1.f; }
      h = tanhf(fmaf(cnt, b1[c], s));
    }
    Yt[(i - 2) * 392 + 256 + c] = f2bf_r(h);          // = Yt[hl][256+c], holds H[r0-2+hl]
  }
  __syncthreads();

  // ---- stage-2: Z rows r0+wave*16..+15; A-frag H row = Yt[wave*16+mrow+j][256+...] ----
  f32x4 acc2[8] = {};
#pragma unroll
  for (int j = 0; j < 3; ++j) {
#pragma unroll
    for (int kk = 0; kk < 4; ++kk) {
      short8 a0 = *(const short8*)&Yt[(wave * 16 + mrow + j) * 392 + 256 + kk * 32 + quad * 8];
      const unsigned short* wp = W2t + (size_t)(j * 128 + mrow) * 128 + kk * 32 + quad * 8;
#pragma unroll
      for (int ct = 0; ct < 8; ++ct)
        acc2[ct] = MFMA16(a0, *(const short8*)(wp + ct * 16 * 128), acc2[ct]);
    }
  }

  // ---- log-softmax per row (128 cols = 16 lanes x 8 ct-regs) ----
#pragma unroll
  for (int rg = 0; rg < 4; ++rg) {
    float z[8]; float m = -1e30f;
#pragma unroll
    for (int ct = 0; ct < 8; ++ct) {
      z[ct] = acc2[ct][rg] + 3.f * b2[ct * 16 + mrow];
      m = fmaxf(m, z[ct]);
    }
#pragma unroll
    for (int off = 1; off < 16; off <<= 1) m = fmaxf(m, __shfl_xor(m, off, 64));
    float s = 0.f;
#pragma unroll
    for (int ct = 0; ct < 8; ++ct) s += __expf(z[ct] - m);
#pragma unroll
    for (int off = 1; off < 16; off <<= 1) s += __shfl_xor(s, off, 64);
    float lse = m + __logf(s);
    int grow = r0 + wave * 16 + quad * 4 + rg;
    if (grow >= 2) {
      float* op = out + (size_t)grow * 128 + mrow;
#pragma unroll
      for (int ct = 0; ct < 8; ++ct) op[ct * 16] = z[ct] - lse;
    }
  }

  // ---- fallback rows 0,1 (block 0): Z0 = tanh(Y[row][0:128]+b1) @ W2[0] + b2 ----
  if (blockIdx.x == 0) {
    __syncthreads();
    int row = tid >> 7, d = tid & 127;
    zbuf[row * 128 + d] = tanhf(bf2f(Yt[(row + 4) * 392 + d]) + b1[d]);  // blk0 cols intact
    __syncthreads();
    float zv = b2[d];
    for (int c = 0; c < 128; ++c)
      zv = fmaf(zbuf[row * 128 + c], bf2f(W2t[(size_t)d * 128 + c]), zv); // W2t[0][d][c]=W2[0][c][d]
    __syncthreads();
    zbuf[row * 128 + d] = zv;
    __syncthreads();
    float m = -1e30f;
    for (int c = 0; c < 128; ++c) m = fmaxf(m, zbuf[row * 128 + c]);
    float s = 0.f;
    for (int c = 0; c < 128; ++c) s += __expf(zbuf[row * 128 + c] - m);
    out[(size_t)row * 128 + d] = zv - m - __logf(s);
  }
}

// ---------- launch ----------
extern "C" void kernel_launch(void* const* d_in, const int* in_sizes, int n_in,
                              void* d_out, int out_size, void* d_ws, size_t ws_size,
                              hipStream_t stream) {
  const float* X  = (const float*)d_in[0];   // [32768, 1, 2048]
  const float* W1 = (const float*)d_in[1];   // [3, 2048, 128]
  const float* b1 = (const float*)d_in[2];   // [1, 128]
  const float* W2 = (const float*)d_in[3];   // [3, 128, 128]
  const float* b2 = (const float*)d_in[4];   // [1, 128]
  float* out = (float*)d_out;                // [32768, 1, 128] fp32

  unsigned short* W1bt = (unsigned short*)d_ws;                    // 384*2048*2 = 1,572,864
  unsigned short* W2t  = (unsigned short*)((char*)d_ws + 1572864); // 98,304

  k_repack<<<288, 256, 0, stream>>>(W1, W2, W1bt, W2t);
  k_fused<<<512, 256, 0, stream>>>(X, W1bt, W2t, b1, b2, out);
}